// Round 5
// baseline (80.526 us; speedup 1.0000x reference)
//
#include <hip/hip_runtime.h>
#include <hip/hip_cooperative_groups.h>

// TensorizedAutoencoder: B=2048, D=512, H=128, K=16, f32 in/out.
// R5: ONE cooperative kernel (143 blocks x 512 thr, all co-resident).
//   P0: distributed exact-f32 argmin assign (block b -> rows 16b..16b+15),
//       __threadfence + grid.sync.
//   P1: per-block redundant bucket scan (LDS hist + wave scan of idx) ->
//       (cluster,tile) 16-row slice -> enc MFMA -> e in LDS -> dec MFMA.
// A-operands split hi+lo bf16 (near-exact); weights bf16 RNE via
// v_cvt_pk_bf16_f32. D-layout per m89: col=l&15, row=4g+reg.

#define BB 2048
#define DD 512
#define HH 128
#define KK 16
#define MAXTILES 143   // max sum of ceil(cnt_k/16) = 128 + 15

namespace cg = cooperative_groups;

typedef float f4v __attribute__((ext_vector_type(4)));
typedef short s8v __attribute__((ext_vector_type(8)));

union U4 { uint4 u; int4 i; s8v v; };

__device__ inline uint pk2(float a, float b) {   // {bf16(a), bf16(b)} packed
    uint r;
    asm("v_cvt_pk_bf16_f32 %0, %1, %2" : "=v"(r) : "v"(a), "v"(b));
    return r;
}
__device__ inline void split2(float a, float b, uint& hi, uint& lo) {
    hi = pk2(a, b);
    const float ha = __uint_as_float(hi << 16);
    const float hb = __uint_as_float(hi & 0xffff0000u);
    lo = pk2(a - ha, b - hb);                    // residual: split self-corrects
}

// Fragment conventions (mfma_f32_16x16x32_bf16, lane l, g=l>>4):
//   A: row=l&15, k=8g+j   B: k=8g+j, col=l&15   D: col=l&15, row=4g+reg [m89]
__global__ __launch_bounds__(512) void ae_k(const float* __restrict__ x,
                                            const float* __restrict__ c,
                                            const float* __restrict__ encW,
                                            const float* __restrict__ encB,
                                            const float* __restrict__ decW,
                                            const float* __restrict__ decB,
                                            int* __restrict__ idx,
                                            float* __restrict__ out) {
    __shared__ int4 frag[2048];          // 32 KB multi-use: hist / enc A / dec A
    __shared__ float e_s[16][132];       // 8.25 KB
    __shared__ int rs_s[16];
    __shared__ ushort cnt_s[KK];
    __shared__ ushort tb_s[KK + 1];

    const int tid = threadIdx.x;
    const int b = blockIdx.x;
    const int w = tid >> 6, l = tid & 63;
    const int r16 = l & 15, g = l >> 4;

    // ---- P0: distributed exact-f32 assignment, block b -> rows 16b+2w(+1) ----
    {
        #pragma unroll
        for (int i = 0; i < 2; ++i) {
            const int row = (b << 4) + (w << 1) + i;
            if (row < BB) {
                const float4* x4 = reinterpret_cast<const float4*>(x + (size_t)row * DD);
                const float4 xa = x4[l * 2];
                const float4 xb = x4[l * 2 + 1];
                float bestd = 3.4e38f;
                int bestk = 0;
                for (int k = 0; k < KK; ++k) {
                    const float4* c4 = reinterpret_cast<const float4*>(c + (size_t)k * DD);
                    const float4 ca = c4[l * 2];
                    const float4 cb = c4[l * 2 + 1];
                    float dotv = xa.x * ca.x + xa.y * ca.y + xa.z * ca.z + xa.w * ca.w
                               + xb.x * cb.x + xb.y * cb.y + xb.z * cb.z + xb.w * cb.w;
                    float cc = ca.x * ca.x + ca.y * ca.y + ca.z * ca.z + ca.w * ca.w
                             + cb.x * cb.x + cb.y * cb.y + cb.z * cb.z + cb.w * cb.w;
                    float v = cc - 2.0f * dotv;   // ||x||^2 const across k (argmin-inv)
                    #pragma unroll
                    for (int off = 32; off > 0; off >>= 1) v += __shfl_xor(v, off, 64);
                    if (v < bestd) { bestd = v; bestk = k; }   // strict <: first-min
                }
                if (l == 0) idx[row] = bestk;
            }
        }
    }
    __threadfence();                     // device-scope release of idx writes
    cg::this_grid().sync();              // all 143 blocks co-resident

    // ---- P1a: redundant per-block bucket scan (deterministic) ----
    ushort (*hist)[KK] = reinterpret_cast<ushort (*)[KK]>(frag);  // [512][16]

    const int4 my = *reinterpret_cast<const int4*>(idx + tid * 4);
    if (tid < 16) rs_s[tid] = -1;
    {
        ushort h[KK];
        #pragma unroll
        for (int k = 0; k < KK; ++k) h[k] = 0;
        h[my.x]++; h[my.y]++; h[my.z]++; h[my.w]++;
        #pragma unroll
        for (int k = 0; k < KK; ++k) hist[tid][k] = h[k];
    }
    __syncthreads();

    // wave w scans clusters 2w, 2w+1 over thread-order (lane l owns t=8l..8l+7)
    #pragma unroll
    for (int kk = 0; kk < 2; ++kk) {
        const int k = w * 2 + kk;
        int v[8], s = 0;
        #pragma unroll
        for (int i = 0; i < 8; ++i) { v[i] = hist[l * 8 + i][k]; s += v[i]; }
        int sc = s;
        #pragma unroll
        for (int off = 1; off < 64; off <<= 1) {
            const int u = __shfl_up(sc, off, 64);
            if (l >= off) sc += u;
        }
        int e = sc - s;                  // exclusive start for t = 8l
        #pragma unroll
        for (int i = 0; i < 8; ++i) { hist[l * 8 + i][k] = (ushort)e; e += v[i]; }
        if (l == 63) cnt_s[k] = (ushort)sc;
    }
    __syncthreads();
    if (tid == 0) {
        int ta = 0;
        for (int k = 0; k < KK; ++k) { tb_s[k] = (ushort)ta; ta += (cnt_s[k] + 15) >> 4; }
        tb_s[KK] = (ushort)ta;
    }
    __syncthreads();
    if (b >= (int)tb_s[KK]) return;      // uniform exit (after grid sync: safe)
    int km = 0;
    #pragma unroll
    for (int kk = 1; kk < KK; ++kk) if (b >= (int)tb_s[kk]) km = kk;
    const int base16 = (b - tb_s[km]) * 16;

    {   // scatter: my rows of cluster km whose rank lands in this tile
        int rank = hist[tid][km];
        const int rv[4] = {my.x, my.y, my.z, my.w};
        #pragma unroll
        for (int i = 0; i < 4; ++i) {
            if (rv[i] == km) {
                if (rank >= base16 && rank < base16 + 16)
                    rs_s[rank - base16] = tid * 4 + i;
                rank++;
            }
        }
    }
    __syncthreads();

    // ---- P1b: stage enc A = bf16split(x[row]-c[km]) in frag layout ----
    int4* Ah = frag;                     // [16 ksteps][64 lanes]
    int4* Al = frag + 1024;
    {
        const int grow = rs_s[r16];
        const int s0 = tid >> 6;
        #pragma unroll
        for (int ss = 0; ss < 2; ++ss) {
            const int s = s0 + ss * 8;
            const int c0 = s * 32 + g * 8;
            float xv[8] = {0.f, 0.f, 0.f, 0.f, 0.f, 0.f, 0.f, 0.f};
            if (grow >= 0) {
                const float4 xa = *(const float4*)(x + (size_t)grow * DD + c0);
                const float4 xb = *(const float4*)(x + (size_t)grow * DD + c0 + 4);
                const float4 ca = *(const float4*)(c + (size_t)km * DD + c0);
                const float4 cb = *(const float4*)(c + (size_t)km * DD + c0 + 4);
                xv[0] = xa.x - ca.x; xv[1] = xa.y - ca.y;
                xv[2] = xa.z - ca.z; xv[3] = xa.w - ca.w;
                xv[4] = xb.x - cb.x; xv[5] = xb.y - cb.y;
                xv[6] = xb.z - cb.z; xv[7] = xb.w - cb.w;
            }
            U4 H, L;
            split2(xv[0], xv[1], H.u.x, L.u.x);
            split2(xv[2], xv[3], H.u.y, L.u.y);
            split2(xv[4], xv[5], H.u.z, L.u.z);
            split2(xv[6], xv[7], H.u.w, L.u.w);
            Ah[s * 64 + l] = H.i;        // lane-linear: conflict-free
            Al[s * 64 + l] = L.i;
        }
    }
    __syncthreads();

    // ---- enc MFMA: wave w owns h-cols [16w,16w+16), K=512 = 16 ksteps ----
    f4v aH = {0.f, 0.f, 0.f, 0.f}, aL = {0.f, 0.f, 0.f, 0.f};
    {
        const float* Wp = encW + (size_t)km * DD * HH + w * 16 + r16;
        #pragma unroll 4
        for (int s = 0; s < 16; ++s) {
            U4 ah, al;
            ah.i = Ah[s * 64 + l];
            al.i = Al[s * 64 + l];
            const float* wp = Wp + (size_t)(s * 32 + g * 8) * HH;
            float bl[8];
            #pragma unroll
            for (int j = 0; j < 8; ++j) bl[j] = wp[(size_t)j * HH];
            U4 bf;
            bf.u = make_uint4(pk2(bl[0], bl[1]), pk2(bl[2], bl[3]),
                              pk2(bl[4], bl[5]), pk2(bl[6], bl[7]));
            aH = __builtin_amdgcn_mfma_f32_16x16x32_bf16(ah.v, bf.v, aH, 0, 0, 0);
            aL = __builtin_amdgcn_mfma_f32_16x16x32_bf16(al.v, bf.v, aL, 0, 0, 0);
        }
        const float bias = encB[km * HH + w * 16 + r16];
        #pragma unroll
        for (int rr = 0; rr < 4; ++rr)
            e_s[g * 4 + rr][w * 16 + r16] = fmaxf(aH[rr] + aL[rr] + bias, 0.f);
    }
    __syncthreads();

    // ---- stage dec A = bf16split(e) in frag layout (256 threads, 1 slot) ----
    int4* Dh = frag;                     // [4 ksteps][64 lanes] (reuse enc bufs)
    int4* Dl = frag + 256;
    if (tid < 256) {
        const int s = tid >> 6, ll = tid & 63;
        const int c0 = s * 32 + (ll >> 4) * 8;
        const float4 ea = *(const float4*)&e_s[ll & 15][c0];
        const float4 eb = *(const float4*)&e_s[ll & 15][c0 + 4];
        U4 H, L;
        split2(ea.x, ea.y, H.u.x, L.u.x);
        split2(ea.z, ea.w, H.u.y, L.u.y);
        split2(eb.x, eb.y, H.u.z, L.u.z);
        split2(eb.z, eb.w, H.u.w, L.u.w);
        Dh[s * 64 + ll] = H.i;
        Dl[s * 64 + ll] = L.i;
    }
    __syncthreads();

    // ---- dec MFMA: wave w owns d-cols [64w,64w+64) = 4 frags, K=128 ----
    f4v dH[4], dL[4];
    #pragma unroll
    for (int f = 0; f < 4; ++f) { dH[f] = (f4v){0.f,0.f,0.f,0.f}; dL[f] = (f4v){0.f,0.f,0.f,0.f}; }
    {
        const float* Vp = decW + (size_t)km * HH * DD + w * 64 + r16;
        #pragma unroll
        for (int s = 0; s < 4; ++s) {
            U4 ah, al;
            ah.i = Dh[s * 64 + l];
            al.i = Dl[s * 64 + l];
            const float* vp = Vp + (size_t)(s * 32 + g * 8) * DD;
            #pragma unroll
            for (int f = 0; f < 4; ++f) {
                float bl[8];
                #pragma unroll
                for (int j = 0; j < 8; ++j) bl[j] = vp[(size_t)j * DD + f * 16];
                U4 bf;
                bf.u = make_uint4(pk2(bl[0], bl[1]), pk2(bl[2], bl[3]),
                                  pk2(bl[4], bl[5]), pk2(bl[6], bl[7]));
                dH[f] = __builtin_amdgcn_mfma_f32_16x16x32_bf16(ah.v, bf.v, dH[f], 0, 0, 0);
                dL[f] = __builtin_amdgcn_mfma_f32_16x16x32_bf16(al.v, bf.v, dL[f], 0, 0, 0);
            }
        }
    }
    // ---- epilogue: + bias -> out ----
    #pragma unroll
    for (int f = 0; f < 4; ++f) {
        const int d = w * 64 + f * 16 + r16;
        const float db = decB[km * DD + d];
        #pragma unroll
        for (int rr = 0; rr < 4; ++rr) {
            const int grow = rs_s[g * 4 + rr];
            if (grow >= 0)
                out[(size_t)grow * DD + d] = dH[f][rr] + dL[f][rr] + db;
        }
    }
}

extern "C" void kernel_launch(void* const* d_in, const int* in_sizes, int n_in,
                              void* d_out, int out_size, void* d_ws, size_t ws_size,
                              hipStream_t stream) {
    const float* x       = (const float*)d_in[0];
    const float* centers = (const float*)d_in[1];
    const float* enc_W   = (const float*)d_in[2];
    const float* enc_b   = (const float*)d_in[3];
    const float* dec_W   = (const float*)d_in[4];
    const float* dec_b   = (const float*)d_in[5];
    float* out = (float*)d_out;
    int* idx = (int*)d_ws;               // 2048 ints, rewritten every call

    void* args[] = { (void*)&x, (void*)&centers, (void*)&enc_W, (void*)&enc_b,
                     (void*)&dec_W, (void*)&dec_b, (void*)&idx, (void*)&out };
    hipLaunchCooperativeKernel((const void*)ae_k, dim3(MAXTILES), dim3(512),
                               args, 0, stream);
}

// Round 7
// 28.948 us; speedup vs baseline: 2.7817x; 2.7817x over previous
//
#include <hip/hip_runtime.h>

// TensorizedAutoencoder: B=2048, D=512, H=128, K=16, f32 in/out.
// R7: R4's exact passing structure (2 kernels, LDS-hist bucketing, MFMA
// enc/dec) with ONE change: hist transposed to [K][512] to kill the 2.3M
// bank-conflict cycles R5's counters exposed (old layout: scan reads were
// 64-way conflicted). Counts computed without dynamic local indexing.
// A-operands hi+lo bf16 split; weights bf16 RNE via v_cvt_pk_bf16_f32.
// D-layout per m89: col=l&15, row=4g+reg.

#define BB 2048
#define DD 512
#define HH 128
#define KK 16
#define MAXTILES 143   // max sum of ceil(cnt_k/16) = 128 + 15

typedef float f4v __attribute__((ext_vector_type(4)));
typedef short s8v __attribute__((ext_vector_type(8)));

union U4 { uint4 u; int4 i; s8v v; };

__device__ inline uint pk2(float a, float b) {   // {bf16(a), bf16(b)} packed
    uint r;
    asm("v_cvt_pk_bf16_f32 %0, %1, %2" : "=v"(r) : "v"(a), "v"(b));
    return r;
}
__device__ inline void split2(float a, float b, uint& hi, uint& lo) {
    hi = pk2(a, b);
    const float ha = __uint_as_float(hi << 16);
    const float hb = __uint_as_float(hi & 0xffff0000u);
    lo = pk2(a - ha, b - hb);                    // residual: split self-corrects
}

__global__ __launch_bounds__(256) void assign_k(const float* __restrict__ x,
                                                const float* __restrict__ c,
                                                int* __restrict__ idx) {
    const int lane = threadIdx.x & 63;
    const int row = (blockIdx.x << 2) + (threadIdx.x >> 6);
    if (row >= BB) return;

    const float4* x4 = reinterpret_cast<const float4*>(x + (size_t)row * DD);
    const float4 xa = x4[lane * 2];
    const float4 xb = x4[lane * 2 + 1];

    float bestd = 3.4e38f;
    int bestk = 0;
    for (int k = 0; k < KK; ++k) {
        const float4* c4 = reinterpret_cast<const float4*>(c + (size_t)k * DD);
        const float4 ca = c4[lane * 2];
        const float4 cb = c4[lane * 2 + 1];
        float dotv = xa.x * ca.x + xa.y * ca.y + xa.z * ca.z + xa.w * ca.w
                   + xb.x * cb.x + xb.y * cb.y + xb.z * cb.z + xb.w * cb.w;
        float cc = ca.x * ca.x + ca.y * ca.y + ca.z * ca.z + ca.w * ca.w
                 + cb.x * cb.x + cb.y * cb.y + cb.z * cb.z + cb.w * cb.w;
        float v = cc - 2.0f * dotv;   // ||x||^2 constant across k (argmin-invariant)
        #pragma unroll
        for (int off = 32; off > 0; off >>= 1) v += __shfl_xor(v, off, 64);
        if (v < bestd) { bestd = v; bestk = k; }   // strict < keeps first-min
    }
    if (lane == 0) idx[row] = bestk;
}

// Fragment conventions (mfma_f32_16x16x32_bf16, lane l, g=l>>4):
//   A: row=l&15, k=8g+j   B: k=8g+j, col=l&15   D: col=l&15, row=4g+reg [m89]
__global__ __launch_bounds__(512) void ae_k(const float* __restrict__ x,
                                            const float* __restrict__ c,
                                            const float* __restrict__ encW,
                                            const float* __restrict__ encB,
                                            const float* __restrict__ decW,
                                            const float* __restrict__ decB,
                                            const int* __restrict__ idx,
                                            float* __restrict__ out) {
    __shared__ int4 frag[2048];          // 32 KB: enc A / dec A frags
    __shared__ ushort hist2[KK][512];    // 16 KB: transposed hist (2-way max)
    __shared__ float e_s[16][132];       // 8.25 KB
    __shared__ int rs_s[16];
    __shared__ ushort cnt_s[KK];
    __shared__ ushort tb_s[KK + 1];

    const int tid = threadIdx.x;
    const int b = blockIdx.x;
    const int w = tid >> 6, l = tid & 63;
    const int r16 = l & 15, g = l >> 4;

    // ---- phase 0: per-thread cluster counts, transposed layout ----
    const int4 my = *reinterpret_cast<const int4*>(idx + tid * 4);
    if (tid < 16) rs_s[tid] = -1;
    #pragma unroll
    for (int k = 0; k < KK; ++k) {
        hist2[k][tid] = (ushort)((my.x == k) + (my.y == k)
                               + (my.z == k) + (my.w == k));
    }
    __syncthreads();

    // wave w scans clusters 2w, 2w+1 over thread-order (lane l owns t=8l..8l+7)
    #pragma unroll
    for (int kk = 0; kk < 2; ++kk) {
        const int k = w * 2 + kk;
        int v[8], s = 0;
        #pragma unroll
        for (int i = 0; i < 8; ++i) { v[i] = hist2[k][l * 8 + i]; s += v[i]; }
        int sc = s;
        #pragma unroll
        for (int off = 1; off < 64; off <<= 1) {
            const int u = __shfl_up(sc, off, 64);
            if (l >= off) sc += u;
        }
        int e = sc - s;                  // exclusive start for t = 8l
        #pragma unroll
        for (int i = 0; i < 8; ++i) { hist2[k][l * 8 + i] = (ushort)e; e += v[i]; }
        if (l == 63) cnt_s[k] = (ushort)sc;
    }
    __syncthreads();
    if (tid == 0) {
        int ta = 0;
        for (int k = 0; k < KK; ++k) { tb_s[k] = (ushort)ta; ta += (cnt_s[k] + 15) >> 4; }
        tb_s[KK] = (ushort)ta;
    }
    __syncthreads();
    if (b >= (int)tb_s[KK]) return;      // uniform exit
    int km = 0;
    #pragma unroll
    for (int kk = 1; kk < KK; ++kk) if (b >= (int)tb_s[kk]) km = kk;
    const int base16 = (b - tb_s[km]) * 16;

    {   // scatter: my rows of cluster km whose rank lands in this tile
        int rank = hist2[km][tid];
        const int rv[4] = {my.x, my.y, my.z, my.w};
        #pragma unroll
        for (int i = 0; i < 4; ++i) {
            if (rv[i] == km) {
                if (rank >= base16 && rank < base16 + 16)
                    rs_s[rank - base16] = tid * 4 + i;
                rank++;
            }
        }
    }
    __syncthreads();

    // ---- stage enc A = bf16split(x[row]-c[km]) in frag layout (2 slots/thr) ----
    int4* Ah = frag;                     // [16 ksteps][64 lanes]
    int4* Al = frag + 1024;
    {
        const int grow = rs_s[r16];
        const int s0 = tid >> 6;
        #pragma unroll
        for (int ss = 0; ss < 2; ++ss) {
            const int s = s0 + ss * 8;
            const int c0 = s * 32 + g * 8;
            float xv[8] = {0.f, 0.f, 0.f, 0.f, 0.f, 0.f, 0.f, 0.f};
            if (grow >= 0) {
                const float4 xa = *(const float4*)(x + (size_t)grow * DD + c0);
                const float4 xb = *(const float4*)(x + (size_t)grow * DD + c0 + 4);
                const float4 ca = *(const float4*)(c + (size_t)km * DD + c0);
                const float4 cb = *(const float4*)(c + (size_t)km * DD + c0 + 4);
                xv[0] = xa.x - ca.x; xv[1] = xa.y - ca.y;
                xv[2] = xa.z - ca.z; xv[3] = xa.w - ca.w;
                xv[4] = xb.x - cb.x; xv[5] = xb.y - cb.y;
                xv[6] = xb.z - cb.z; xv[7] = xb.w - cb.w;
            }
            U4 H, L;
            split2(xv[0], xv[1], H.u.x, L.u.x);
            split2(xv[2], xv[3], H.u.y, L.u.y);
            split2(xv[4], xv[5], H.u.z, L.u.z);
            split2(xv[6], xv[7], H.u.w, L.u.w);
            Ah[s * 64 + l] = H.i;        // lane-linear: conflict-free
            Al[s * 64 + l] = L.i;
        }
    }
    __syncthreads();

    // ---- enc MFMA: wave w owns h-cols [16w,16w+16), K=512 = 16 ksteps ----
    f4v aH = {0.f, 0.f, 0.f, 0.f}, aL = {0.f, 0.f, 0.f, 0.f};
    {
        const float* Wp = encW + (size_t)km * DD * HH + w * 16 + r16;
        #pragma unroll 4
        for (int s = 0; s < 16; ++s) {
            U4 ah, al;
            ah.i = Ah[s * 64 + l];
            al.i = Al[s * 64 + l];
            const float* wp = Wp + (size_t)(s * 32 + g * 8) * HH;
            float bl[8];
            #pragma unroll
            for (int j = 0; j < 8; ++j) bl[j] = wp[(size_t)j * HH];
            U4 bf;
            bf.u = make_uint4(pk2(bl[0], bl[1]), pk2(bl[2], bl[3]),
                              pk2(bl[4], bl[5]), pk2(bl[6], bl[7]));
            aH = __builtin_amdgcn_mfma_f32_16x16x32_bf16(ah.v, bf.v, aH, 0, 0, 0);
            aL = __builtin_amdgcn_mfma_f32_16x16x32_bf16(al.v, bf.v, aL, 0, 0, 0);
        }
        const float bias = encB[km * HH + w * 16 + r16];
        #pragma unroll
        for (int rr = 0; rr < 4; ++rr)
            e_s[g * 4 + rr][w * 16 + r16] = fmaxf(aH[rr] + aL[rr] + bias, 0.f);
    }
    __syncthreads();

    // ---- stage dec A = bf16split(e) in frag layout (256 threads, 1 slot) ----
    int4* Dh = frag;                     // [4 ksteps][64 lanes] (reuse enc bufs)
    int4* Dl = frag + 256;
    if (tid < 256) {
        const int s = tid >> 6, ll = tid & 63;
        const int c0 = s * 32 + (ll >> 4) * 8;
        const float4 ea = *(const float4*)&e_s[ll & 15][c0];
        const float4 eb = *(const float4*)&e_s[ll & 15][c0 + 4];
        U4 H, L;
        split2(ea.x, ea.y, H.u.x, L.u.x);
        split2(ea.z, ea.w, H.u.y, L.u.y);
        split2(eb.x, eb.y, H.u.z, L.u.z);
        split2(eb.z, eb.w, H.u.w, L.u.w);
        Dh[s * 64 + ll] = H.i;
        Dl[s * 64 + ll] = L.i;
    }
    __syncthreads();

    // ---- dec MFMA: wave w owns d-cols [64w,64w+64) = 4 frags, K=128 ----
    f4v dH[4], dL[4];
    #pragma unroll
    for (int f = 0; f < 4; ++f) { dH[f] = (f4v){0.f,0.f,0.f,0.f}; dL[f] = (f4v){0.f,0.f,0.f,0.f}; }
    {
        const float* Vp = decW + (size_t)km * HH * DD + w * 64 + r16;
        #pragma unroll
        for (int s = 0; s < 4; ++s) {
            U4 ah, al;
            ah.i = Dh[s * 64 + l];
            al.i = Dl[s * 64 + l];
            const float* vp = Vp + (size_t)(s * 32 + g * 8) * DD;
            #pragma unroll
            for (int f = 0; f < 4; ++f) {
                float bl[8];
                #pragma unroll
                for (int j = 0; j < 8; ++j) bl[j] = vp[(size_t)j * DD + f * 16];
                U4 bf;
                bf.u = make_uint4(pk2(bl[0], bl[1]), pk2(bl[2], bl[3]),
                                  pk2(bl[4], bl[5]), pk2(bl[6], bl[7]));
                dH[f] = __builtin_amdgcn_mfma_f32_16x16x32_bf16(ah.v, bf.v, dH[f], 0, 0, 0);
                dL[f] = __builtin_amdgcn_mfma_f32_16x16x32_bf16(al.v, bf.v, dL[f], 0, 0, 0);
            }
        }
    }
    // ---- epilogue: + bias -> out ----
    #pragma unroll
    for (int f = 0; f < 4; ++f) {
        const int d = w * 64 + f * 16 + r16;
        const float db = decB[km * DD + d];
        #pragma unroll
        for (int rr = 0; rr < 4; ++rr) {
            const int grow = rs_s[g * 4 + rr];
            if (grow >= 0)
                out[(size_t)grow * DD + d] = dH[f][rr] + dL[f][rr] + db;
        }
    }
}

extern "C" void kernel_launch(void* const* d_in, const int* in_sizes, int n_in,
                              void* d_out, int out_size, void* d_ws, size_t ws_size,
                              hipStream_t stream) {
    const float* x       = (const float*)d_in[0];
    const float* centers = (const float*)d_in[1];
    const float* enc_W   = (const float*)d_in[2];
    const float* enc_b   = (const float*)d_in[3];
    const float* dec_W   = (const float*)d_in[4];
    const float* dec_b   = (const float*)d_in[5];
    float* out = (float*)d_out;
    int* idx = (int*)d_ws;               // 2048 ints, rewritten every call

    assign_k<<<BB / 4, 256, 0, stream>>>(x, centers, idx);
    ae_k<<<MAXTILES, 512, 0, stream>>>(x, centers, enc_W, enc_b, dec_W, dec_b,
                                       idx, out);
}

// Round 8
// 27.837 us; speedup vs baseline: 2.8928x; 1.0399x over previous
//
#include <hip/hip_runtime.h>

// TensorizedAutoencoder: B=2048, D=512, H=128, K=16, f32 in/out.
// R8: R7 (passing, 28.9us) + batched weight prefetch. Each wave issues 64
// independent weight loads (8 ksteps/frags) into statically-indexed register
// arrays before pack/MFMA, double-batched so batch-1 loads fly during batch-0
// MFMAs; dec batch-0 issued during e-staging. Same addresses, same MFMA
// order -> bit-identical to R7. Attacks the per-kstep cold-load stalls
// (weights ~8MB fetched from HBM every dispatch, FETCH_SIZE evidence).

#define BB 2048
#define DD 512
#define HH 128
#define KK 16
#define MAXTILES 143   // max sum of ceil(cnt_k/16) = 128 + 15

typedef float f4v __attribute__((ext_vector_type(4)));
typedef short s8v __attribute__((ext_vector_type(8)));

union U4 { uint4 u; int4 i; s8v v; };

__device__ inline uint pk2(float a, float b) {   // {bf16(a), bf16(b)} packed
    uint r;
    asm("v_cvt_pk_bf16_f32 %0, %1, %2" : "=v"(r) : "v"(a), "v"(b));
    return r;
}
__device__ inline void split2(float a, float b, uint& hi, uint& lo) {
    hi = pk2(a, b);
    const float ha = __uint_as_float(hi << 16);
    const float hb = __uint_as_float(hi & 0xffff0000u);
    lo = pk2(a - ha, b - hb);                    // residual: split self-corrects
}
__device__ inline U4 packrow(const float* bl) {
    U4 r;
    r.u = make_uint4(pk2(bl[0], bl[1]), pk2(bl[2], bl[3]),
                     pk2(bl[4], bl[5]), pk2(bl[6], bl[7]));
    return r;
}

__global__ __launch_bounds__(256) void assign_k(const float* __restrict__ x,
                                                const float* __restrict__ c,
                                                int* __restrict__ idx) {
    const int lane = threadIdx.x & 63;
    const int row = (blockIdx.x << 2) + (threadIdx.x >> 6);
    if (row >= BB) return;

    const float4* x4 = reinterpret_cast<const float4*>(x + (size_t)row * DD);
    const float4 xa = x4[lane * 2];
    const float4 xb = x4[lane * 2 + 1];

    float bestd = 3.4e38f;
    int bestk = 0;
    for (int k = 0; k < KK; ++k) {
        const float4* c4 = reinterpret_cast<const float4*>(c + (size_t)k * DD);
        const float4 ca = c4[lane * 2];
        const float4 cb = c4[lane * 2 + 1];
        float dotv = xa.x * ca.x + xa.y * ca.y + xa.z * ca.z + xa.w * ca.w
                   + xb.x * cb.x + xb.y * cb.y + xb.z * cb.z + xb.w * cb.w;
        float cc = ca.x * ca.x + ca.y * ca.y + ca.z * ca.z + ca.w * ca.w
                 + cb.x * cb.x + cb.y * cb.y + cb.z * cb.z + cb.w * cb.w;
        float v = cc - 2.0f * dotv;   // ||x||^2 constant across k (argmin-invariant)
        #pragma unroll
        for (int off = 32; off > 0; off >>= 1) v += __shfl_xor(v, off, 64);
        if (v < bestd) { bestd = v; bestk = k; }   // strict < keeps first-min
    }
    if (lane == 0) idx[row] = bestk;
}

// Fragment conventions (mfma_f32_16x16x32_bf16, lane l, g=l>>4):
//   A: row=l&15, k=8g+j   B: k=8g+j, col=l&15   D: col=l&15, row=4g+reg [m89]
__global__ __launch_bounds__(512) void ae_k(const float* __restrict__ x,
                                            const float* __restrict__ c,
                                            const float* __restrict__ encW,
                                            const float* __restrict__ encB,
                                            const float* __restrict__ decW,
                                            const float* __restrict__ decB,
                                            const int* __restrict__ idx,
                                            float* __restrict__ out) {
    __shared__ int4 frag[2048];          // 32 KB: enc A / dec A frags
    __shared__ ushort hist2[KK][512];    // 16 KB: transposed hist (2-way max)
    __shared__ float e_s[16][132];       // 8.25 KB
    __shared__ int rs_s[16];
    __shared__ ushort cnt_s[KK];
    __shared__ ushort tb_s[KK + 1];

    const int tid = threadIdx.x;
    const int b = blockIdx.x;
    const int w = tid >> 6, l = tid & 63;
    const int r16 = l & 15, g = l >> 4;

    // ---- phase 0: per-thread cluster counts, transposed layout ----
    const int4 my = *reinterpret_cast<const int4*>(idx + tid * 4);
    if (tid < 16) rs_s[tid] = -1;
    #pragma unroll
    for (int k = 0; k < KK; ++k) {
        hist2[k][tid] = (ushort)((my.x == k) + (my.y == k)
                               + (my.z == k) + (my.w == k));
    }
    __syncthreads();

    // wave w scans clusters 2w, 2w+1 over thread-order (lane l owns t=8l..8l+7)
    #pragma unroll
    for (int kk = 0; kk < 2; ++kk) {
        const int k = w * 2 + kk;
        int v[8], s = 0;
        #pragma unroll
        for (int i = 0; i < 8; ++i) { v[i] = hist2[k][l * 8 + i]; s += v[i]; }
        int sc = s;
        #pragma unroll
        for (int off = 1; off < 64; off <<= 1) {
            const int u = __shfl_up(sc, off, 64);
            if (l >= off) sc += u;
        }
        int e = sc - s;                  // exclusive start for t = 8l
        #pragma unroll
        for (int i = 0; i < 8; ++i) { hist2[k][l * 8 + i] = (ushort)e; e += v[i]; }
        if (l == 63) cnt_s[k] = (ushort)sc;
    }
    __syncthreads();
    if (tid == 0) {
        int ta = 0;
        for (int k = 0; k < KK; ++k) { tb_s[k] = (ushort)ta; ta += (cnt_s[k] + 15) >> 4; }
        tb_s[KK] = (ushort)ta;
    }
    __syncthreads();
    if (b >= (int)tb_s[KK]) return;      // uniform exit
    int km = 0;
    #pragma unroll
    for (int kk = 1; kk < KK; ++kk) if (b >= (int)tb_s[kk]) km = kk;
    const int base16 = (b - tb_s[km]) * 16;

    {   // scatter: my rows of cluster km whose rank lands in this tile
        int rank = hist2[km][tid];
        const int rv[4] = {my.x, my.y, my.z, my.w};
        #pragma unroll
        for (int i = 0; i < 4; ++i) {
            if (rv[i] == km) {
                if (rank >= base16 && rank < base16 + 16)
                    rs_s[rank - base16] = tid * 4 + i;
                rank++;
            }
        }
    }
    __syncthreads();

    // ---- issue enc weight batch 0 (s=0..7): 64 independent loads ----
    const float* Wp = encW + (size_t)km * DD * HH + w * 16 + r16;
    float bl0[8][8];
    #pragma unroll
    for (int s = 0; s < 8; ++s)
        #pragma unroll
        for (int j = 0; j < 8; ++j)
            bl0[s][j] = Wp[(size_t)(s * 32 + g * 8 + j) * HH];

    // ---- stage enc A = bf16split(x[row]-c[km]) in frag layout (2 slots/thr) ----
    int4* Ah = frag;                     // [16 ksteps][64 lanes]
    int4* Al = frag + 1024;
    {
        const int grow = rs_s[r16];
        const int s0 = tid >> 6;
        #pragma unroll
        for (int ss = 0; ss < 2; ++ss) {
            const int s = s0 + ss * 8;
            const int c0 = s * 32 + g * 8;
            float xv[8] = {0.f, 0.f, 0.f, 0.f, 0.f, 0.f, 0.f, 0.f};
            if (grow >= 0) {
                const float4 xa = *(const float4*)(x + (size_t)grow * DD + c0);
                const float4 xb = *(const float4*)(x + (size_t)grow * DD + c0 + 4);
                const float4 ca = *(const float4*)(c + (size_t)km * DD + c0);
                const float4 cb = *(const float4*)(c + (size_t)km * DD + c0 + 4);
                xv[0] = xa.x - ca.x; xv[1] = xa.y - ca.y;
                xv[2] = xa.z - ca.z; xv[3] = xa.w - ca.w;
                xv[4] = xb.x - cb.x; xv[5] = xb.y - cb.y;
                xv[6] = xb.z - cb.z; xv[7] = xb.w - cb.w;
            }
            U4 H, L;
            split2(xv[0], xv[1], H.u.x, L.u.x);
            split2(xv[2], xv[3], H.u.y, L.u.y);
            split2(xv[4], xv[5], H.u.z, L.u.z);
            split2(xv[6], xv[7], H.u.w, L.u.w);
            Ah[s * 64 + l] = H.i;        // lane-linear: conflict-free
            Al[s * 64 + l] = L.i;
        }
    }
    __syncthreads();

    // ---- enc MFMA: wave w owns h-cols [16w,16w+16), K=512, 2 batches ----
    f4v aH = {0.f, 0.f, 0.f, 0.f}, aL = {0.f, 0.f, 0.f, 0.f};
    {
        U4 bf0[8];
        #pragma unroll
        for (int s = 0; s < 8; ++s) bf0[s] = packrow(bl0[s]);   // waits batch 0

        float bl1[8][8];                 // issue batch 1 before MFMA batch 0
        #pragma unroll
        for (int s = 0; s < 8; ++s)
            #pragma unroll
            for (int j = 0; j < 8; ++j)
                bl1[s][j] = Wp[(size_t)((s + 8) * 32 + g * 8 + j) * HH];

        #pragma unroll
        for (int s = 0; s < 8; ++s) {
            U4 ah, al;
            ah.i = Ah[s * 64 + l];
            al.i = Al[s * 64 + l];
            aH = __builtin_amdgcn_mfma_f32_16x16x32_bf16(ah.v, bf0[s].v, aH, 0, 0, 0);
            aL = __builtin_amdgcn_mfma_f32_16x16x32_bf16(al.v, bf0[s].v, aL, 0, 0, 0);
        }
        U4 bf1[8];
        #pragma unroll
        for (int s = 0; s < 8; ++s) bf1[s] = packrow(bl1[s]);   // waits batch 1
        #pragma unroll
        for (int s = 8; s < 16; ++s) {
            U4 ah, al;
            ah.i = Ah[s * 64 + l];
            al.i = Al[s * 64 + l];
            aH = __builtin_amdgcn_mfma_f32_16x16x32_bf16(ah.v, bf1[s - 8].v, aH, 0, 0, 0);
            aL = __builtin_amdgcn_mfma_f32_16x16x32_bf16(al.v, bf1[s - 8].v, aL, 0, 0, 0);
        }
        const float bias = encB[km * HH + w * 16 + r16];
        #pragma unroll
        for (int rr = 0; rr < 4; ++rr)
            e_s[g * 4 + rr][w * 16 + r16] = fmaxf(aH[rr] + aL[rr] + bias, 0.f);
    }

    // ---- issue dec weight batch 0 (s=0..1, f=0..3) during e-staging ----
    const float* Vp = decW + (size_t)km * HH * DD + w * 64 + r16;
    float cl0[8][8];                     // p = s*4+f
    #pragma unroll
    for (int p = 0; p < 8; ++p)
        #pragma unroll
        for (int j = 0; j < 8; ++j)
            cl0[p][j] = Vp[(size_t)((p >> 2) * 32 + g * 8 + j) * DD + (p & 3) * 16];

    __syncthreads();

    // ---- stage dec A = bf16split(e) in frag layout (256 threads, 1 slot) ----
    int4* Dh = frag;                     // [4 ksteps][64 lanes] (reuse enc bufs)
    int4* Dl = frag + 256;
    if (tid < 256) {
        const int s = tid >> 6, ll = tid & 63;
        const int c0 = s * 32 + (ll >> 4) * 8;
        const float4 ea = *(const float4*)&e_s[ll & 15][c0];
        const float4 eb = *(const float4*)&e_s[ll & 15][c0 + 4];
        U4 H, L;
        split2(ea.x, ea.y, H.u.x, L.u.x);
        split2(ea.z, ea.w, H.u.y, L.u.y);
        split2(eb.x, eb.y, H.u.z, L.u.z);
        split2(eb.z, eb.w, H.u.w, L.u.w);
        Dh[s * 64 + ll] = H.i;
        Dl[s * 64 + ll] = L.i;
    }
    __syncthreads();

    // ---- dec MFMA: wave w owns d-cols [64w,64w+64) = 4 frags, K=128 ----
    f4v dH[4], dL[4];
    #pragma unroll
    for (int f = 0; f < 4; ++f) { dH[f] = (f4v){0.f,0.f,0.f,0.f}; dL[f] = (f4v){0.f,0.f,0.f,0.f}; }
    {
        U4 cf0[8];
        #pragma unroll
        for (int p = 0; p < 8; ++p) cf0[p] = packrow(cl0[p]);   // waits batch 0

        float cl1[8][8];                 // issue batch 1 (s=2..3) before MFMAs
        #pragma unroll
        for (int p = 0; p < 8; ++p)
            #pragma unroll
            for (int j = 0; j < 8; ++j)
                cl1[p][j] = Vp[(size_t)(((p >> 2) + 2) * 32 + g * 8 + j) * DD + (p & 3) * 16];

        #pragma unroll
        for (int s = 0; s < 2; ++s) {
            U4 ah, al;
            ah.i = Dh[s * 64 + l];
            al.i = Dl[s * 64 + l];
            #pragma unroll
            for (int f = 0; f < 4; ++f) {
                dH[f] = __builtin_amdgcn_mfma_f32_16x16x32_bf16(ah.v, cf0[s * 4 + f].v, dH[f], 0, 0, 0);
                dL[f] = __builtin_amdgcn_mfma_f32_16x16x32_bf16(al.v, cf0[s * 4 + f].v, dL[f], 0, 0, 0);
            }
        }
        U4 cf1[8];
        #pragma unroll
        for (int p = 0; p < 8; ++p) cf1[p] = packrow(cl1[p]);   // waits batch 1
        #pragma unroll
        for (int s = 2; s < 4; ++s) {
            U4 ah, al;
            ah.i = Dh[s * 64 + l];
            al.i = Dl[s * 64 + l];
            #pragma unroll
            for (int f = 0; f < 4; ++f) {
                dH[f] = __builtin_amdgcn_mfma_f32_16x16x32_bf16(ah.v, cf1[(s - 2) * 4 + f].v, dH[f], 0, 0, 0);
                dL[f] = __builtin_amdgcn_mfma_f32_16x16x32_bf16(al.v, cf1[(s - 2) * 4 + f].v, dL[f], 0, 0, 0);
            }
        }
    }
    // ---- epilogue: + bias -> out ----
    #pragma unroll
    for (int f = 0; f < 4; ++f) {
        const int d = w * 64 + f * 16 + r16;
        const float db = decB[km * DD + d];
        #pragma unroll
        for (int rr = 0; rr < 4; ++rr) {
            const int grow = rs_s[g * 4 + rr];
            if (grow >= 0)
                out[(size_t)grow * DD + d] = dH[f][rr] + dL[f][rr] + db;
        }
    }
}

extern "C" void kernel_launch(void* const* d_in, const int* in_sizes, int n_in,
                              void* d_out, int out_size, void* d_ws, size_t ws_size,
                              hipStream_t stream) {
    const float* x       = (const float*)d_in[0];
    const float* centers = (const float*)d_in[1];
    const float* enc_W   = (const float*)d_in[2];
    const float* enc_b   = (const float*)d_in[3];
    const float* dec_W   = (const float*)d_in[4];
    const float* dec_b   = (const float*)d_in[5];
    float* out = (float*)d_out;
    int* idx = (int*)d_ws;               // 2048 ints, rewritten every call

    assign_k<<<BB / 4, 256, 0, stream>>>(x, centers, idx);
    ae_k<<<MAXTILES, 512, 0, stream>>>(x, centers, enc_W, enc_b, dec_W, dec_b,
                                       idx, out);
}